// Round 7
// baseline (234.167 us; speedup 1.0000x reference)
//
#include <hip/hip_runtime.h>
#include <hip/hip_bf16.h>

#define NB 4
#define CH 256
#define HH 64
#define WW 64
#define NPIX 4096      // HH*WW
#define OH 62
#define NPATCH 3844    // 62*62
#define KDIM 256       // == CH
#define EPSN 1e-12f
#define SEG 8          // diagonal segment length (row-pairs per block)
#define PST 68         // k_prep stage row stride (shorts): 8B-aligned rows

typedef __attribute__((ext_vector_type(8))) short short8;
typedef __attribute__((ext_vector_type(4))) float f32x4;

__device__ __forceinline__ float bf16_to_f32(unsigned short u) {
    return __uint_as_float((unsigned)u << 16);
}
__device__ __forceinline__ unsigned short f32_to_bf16(float f) {
    __hip_bfloat16 h = __float2bfloat16(f);
    return *(unsigned short*)&h;
}

// ---- K1 (fused prep): read inputs ONCE; per-pixel ss + inv-norm; normalized bf16
// ---- transpose (C,pix)->(pix,C). Also zero-inits d_out + keys.
__global__ __launch_bounds__(256) void k_prep(const float* __restrict__ pred,
                                              const float* __restrict__ tgt,
                                              __hip_bfloat16* __restrict__ Xn,
                                              __hip_bfloat16* __restrict__ Tn,
                                              float* __restrict__ ssP, float* __restrict__ invP,
                                              float* __restrict__ ssT, float* __restrict__ invT,
                                              unsigned long long* __restrict__ keys,
                                              float* __restrict__ out) {
    const int bz = blockIdx.y;            // 0..7
    const int b = bz >> 1, which = bz & 1;
    const float* src = (which ? tgt : pred) + (size_t)b * CH * NPIX;
    unsigned short* dst = (unsigned short*)((which ? Tn : Xn) + (size_t)b * NPIX * CH);
    float* ss_g  = (which ? ssT  : ssP)  + b * NPIX;
    float* inv_g = (which ? invT : invP) + b * NPIX;
    const int pix0 = blockIdx.x * 64;
    const int t = threadIdx.x, lane = t & 63, wv = t >> 6;

    int gid = (bz * 64 + blockIdx.x) * 256 + t;
    if (gid < NB * NPATCH) keys[gid] = 0ull;
    if (gid == 0) out[0] = 0.f;

    __shared__ unsigned short stage[CH][PST];  // 34816 B
    __shared__ float partial[16][68];          // 4352 B (+pad: 2-way reads)
    __shared__ float inv_s[64];

    // load: thread (cb = t>>4, ch = t&15) covers c = cb*16+r (r<16), pixels ch*4..+3
    const int cb = t >> 4, chk = t & 15;
    float ss0 = 0.f, ss1 = 0.f, ss2 = 0.f, ss3 = 0.f;
#pragma unroll
    for (int r = 0; r < 16; ++r) {
        int c = cb * 16 + r;
        float4 v = *(const float4*)&src[(size_t)c * NPIX + pix0 + chk * 4];
        ss0 += v.x * v.x; ss1 += v.y * v.y; ss2 += v.z * v.z; ss3 += v.w * v.w;
        ushort4 sv;
        sv.x = f32_to_bf16(v.x); sv.y = f32_to_bf16(v.y);
        sv.z = f32_to_bf16(v.z); sv.w = f32_to_bf16(v.w);
        *(ushort4*)&stage[c][chk * 4] = sv;
    }
    float4 pv; pv.x = ss0; pv.y = ss1; pv.z = ss2; pv.w = ss3;
    *(float4*)&partial[cb][chk * 4] = pv;
    __syncthreads();
    if (t < 64) {
        float ss = 0.f;
#pragma unroll
        for (int r = 0; r < 16; ++r) ss += partial[r][t];
        float inv = 1.f / fmaxf(sqrtf(ss), EPSN);
        ss_g[pix0 + t] = ss;
        inv_g[pix0 + t] = inv;
        inv_s[t] = inv;
    }
    __syncthreads();
    // write: pixel p (16/wave), lane = c within 64-chunk; 2-way-free LDS reads
    for (int p = wv; p < 64; p += 4) {
        float iv = inv_s[p];
#pragma unroll
        for (int cc = 0; cc < 4; ++cc) {
            int c = cc * 64 + lane;
            float v = bf16_to_f32(stage[c][p]) * iv;
            dst[(size_t)(pix0 + p) * CH + c] = f32_to_bf16(v);
        }
    }
}

// ------- K2: D = Xn * Tn^T (4096x4096, K=256, bf16 MFMA, bf16 OUTPUT).
// LOCKED R1/R3 inner config (57.3 us combined, three independent measurements).
// R7: FOUR z-dispatches (~14.3 us each) purely for rocprof visibility of
// k_prep / k_loss. Swizzle over 1024 blocks (%8==0, bijective).
__device__ __forceinline__ void gload_lds16(const void* g, void* l) {
    __builtin_amdgcn_global_load_lds(
        (const __attribute__((address_space(1))) void*)g,
        (__attribute__((address_space(3))) void*)l, 16, 0, 0);
}

__global__ __launch_bounds__(256, 2) void k_gemm(const __hip_bfloat16* __restrict__ A,
                                                 const __hip_bfloat16* __restrict__ Bm,
                                                 unsigned short* __restrict__ Dout,
                                                 int zbase) {
    // one 64 KB arena: As buf0 [0,8192), As buf1 [8192,16384),
    //                  Bs buf0 [16384,24576), Bs buf1 [24576,32768) (shorts)
    __shared__ __align__(16) short smem[32768];
#define ASOFF(buf) ((buf) * 8192)
#define BSOFF(buf) (16384 + (buf) * 8192)

    const int t = threadIdx.x;
    const int lane = t & 63, wv = t >> 6;          // 4 waves
    const int wm = wv >> 1, wn = wv & 1;           // 2x2 wave grid, 64x64 each

    // XCD-bijective swizzle over 1024 blocks (nwg%8==0)
    const int bid = blockIdx.y * 32 + blockIdx.x;  // 0..1023
    const int swz = ((bid & 7) << 7) + (bid >> 3);
    const int z = zbase, by = swz >> 5, bx = swz & 31;

    const int row0 = by * 128, col0 = bx * 128;
    const short* Ag = (const short*)A + (size_t)z * NPIX * CH;
    const short* Bg = (const short*)Bm + (size_t)z * NPIX * CH;
    unsigned short* D = Dout + (size_t)z * NPIX * NPIX;

    const int srow = t >> 3;                        // 0..31 (staging row within round)
    const int kce  = ((t & 7) ^ (srow & 7)) * 8;    // pre-swizzled k offset within BK=64

    f32x4 acc[4][4] = {};

    // stage one BK=64 K-slab of A(128x64) + B(128x64): 4 rounds each, 8 loads/thread
#define STAGE_K(buf, k0)                                                                   \
    do {                                                                                   \
        _Pragma("unroll")                                                                  \
        for (int rr_ = 0; rr_ < 4; ++rr_)                                                  \
            gload_lds16(Ag + (size_t)(row0 + rr_ * 32 + srow) * KDIM + (k0) + kce,         \
                        &smem[ASOFF(buf) + rr_ * 2048 + wv * 512]);                        \
        _Pragma("unroll")                                                                  \
        for (int rr_ = 0; rr_ < 4; ++rr_)                                                  \
            gload_lds16(Bg + (size_t)(col0 + rr_ * 32 + srow) * KDIM + (k0) + kce,         \
                        &smem[BSOFF(buf) + rr_ * 2048 + wv * 512]);                        \
    } while (0)

    const int rsel = lane & 15, kq = lane >> 4;
    const int rx = rsel & 7;

#define CONSUME(buf)                                                                       \
    do {                                                                                   \
        _Pragma("unroll")                                                                  \
        for (int s = 0; s < 2; ++s) {                                                      \
            const int pk = (((s << 2) + kq) ^ rx) * 8;                                     \
            short8 a_[4], b_[4];                                                           \
            _Pragma("unroll")                                                              \
            for (int mi = 0; mi < 4; ++mi)                                                 \
                a_[mi] = *(const short8*)&smem[ASOFF(buf) + (wm * 64 + mi * 16 + rsel) * 64 + pk]; \
            _Pragma("unroll")                                                              \
            for (int ni = 0; ni < 4; ++ni)                                                 \
                b_[ni] = *(const short8*)&smem[BSOFF(buf) + (wn * 64 + ni * 16 + rsel) * 64 + pk]; \
            _Pragma("unroll")                                                              \
            for (int mi = 0; mi < 4; ++mi)                                                 \
                _Pragma("unroll")                                                          \
                for (int ni = 0; ni < 4; ++ni)                                             \
                    acc[mi][ni] = __builtin_amdgcn_mfma_f32_16x16x32_bf16(a_[mi], b_[ni],  \
                                                                          acc[mi][ni], 0, 0, 0); \
        }                                                                                  \
    } while (0)

#define KITER(it, VMC)                                              \
    do {                                                            \
        asm volatile("s_waitcnt vmcnt(" #VMC ")" ::: "memory");     \
        __builtin_amdgcn_sched_barrier(0);                          \
        __builtin_amdgcn_s_barrier();                               \
        __builtin_amdgcn_sched_barrier(0);                          \
        CONSUME((it) & 1);                                          \
        asm volatile("s_waitcnt lgkmcnt(0)" ::: "memory");          \
        __builtin_amdgcn_sched_barrier(0);                          \
        __builtin_amdgcn_s_barrier();                               \
        __builtin_amdgcn_sched_barrier(0);                          \
        if ((it) < 2) STAGE_K((it) & 1, ((it) + 2) * 64);           \
    } while (0)

    STAGE_K(0, 0);
    STAGE_K(1, 64);        // 16 loads in flight
    KITER(0, 8);
    KITER(1, 8);
    KITER(2, 8);
    KITER(3, 0);
#undef KITER
#undef CONSUME
#undef STAGE_K

    // ---- epilogue: stage C tile (128x128 bf16, 32 KB) in LDS, store dwordx4 ----
    const int rbase = (lane >> 4) * 4, cbase = lane & 15;
    unsigned short* Cs = (unsigned short*)smem;
#pragma unroll
    for (int mi = 0; mi < 4; ++mi)
#pragma unroll
        for (int ni = 0; ni < 4; ++ni) {
            int c = wn * 64 + ni * 16 + cbase;
#pragma unroll
            for (int r = 0; r < 4; ++r) {
                int row = wm * 64 + mi * 16 + rbase + r;
                int pc = (((c >> 3) ^ (row & 15)) * 8) + (c & 7);
                Cs[row * 128 + pc] = f32_to_bf16(acc[mi][ni][r]);
            }
        }
    __syncthreads();
#pragma unroll
    for (int rd = 0; rd < 8; ++rd) {
        int rr = rd * 16 + (t >> 4);
        int pc = ((t & 15) ^ (rr & 15)) * 8;
        uint4 v = *(const uint4*)&Cs[rr * 128 + pc];
        *(uint4*)&D[(size_t)(row0 + rr) * NPIX + col0 + (t & 15) * 8] = v;
    }
#undef ASOFF
#undef BSOFF
}

// ---- K3 (k_score): barrier-free, LDS-free streaming formulation (R6; 46.5 us,
// WRITE 8.4 MB, 0 conflicts — kept). R7: split into FOUR INTERLEAVED segment
// dispatches (s0 = (by*4 + ybase)*SEG, grid 123x2x4) for rocprof visibility;
// interleaving balances useful-block counts (~16/13/10/8 us quarters).
__device__ __forceinline__ void load_row18(const unsigned short* __restrict__ rp,
                                           bool full, float* o) {
    uint4 u0 = *(const uint4*)rp;          // cols 0..7
    uint4 u1 = *(const uint4*)(rp + 8);    // cols 8..15
    unsigned e = full ? *(const unsigned*)(rp + 16) : 0u;  // cols 16,17
    const unsigned* w0 = (const unsigned*)&u0;
    const unsigned* w1 = (const unsigned*)&u1;
#pragma unroll
    for (int w = 0; w < 4; ++w) {
        o[2 * w]         = bf16_to_f32((unsigned short)w0[w]);
        o[2 * w + 1]     = bf16_to_f32((unsigned short)(w0[w] >> 16));
        o[8 + 2 * w]     = bf16_to_f32((unsigned short)w1[w]);
        o[8 + 2 * w + 1] = bf16_to_f32((unsigned short)(w1[w] >> 16));
    }
    o[16] = bf16_to_f32((unsigned short)e);
    o[17] = bf16_to_f32((unsigned short)(e >> 16));
}

__device__ __forceinline__ void gtile(const unsigned short* __restrict__ D,
                                      int tr, int tc, int a, int b0, bool full,
                                      float* G) {
    const unsigned short* base = D + (size_t)(tr * 64 + a) * NPIX + tc * 64 + b0;
    float r0[18], r1[18], r2[18];
    load_row18(base, full, r0);
    load_row18(base + NPIX, full, r1);
    load_row18(base + 2 * NPIX, full, r2);
#pragma unroll
    for (int kk = 0; kk < 16; ++kk)
        G[kk] = r0[kk] + r1[kk + 1] + r2[kk + 2];
}

__global__ __launch_bounds__(256) void k_score(const unsigned short* __restrict__ Dbase,
                                               unsigned long long* __restrict__ keys,
                                               int ybase) {
    const int z = blockIdx.z;
    const unsigned short* D = Dbase + (size_t)z * NPIX * NPIX;
    const int t = threadIdx.x;

    const int d = (int)blockIdx.x - 61;            // diagonal qr-pr in [-61, 61]
    const int adg = d < 0 ? -d : d;
    const int len = 62 - adg;
    const int s0 = (blockIdx.y * 4 + ybase) * SEG;
    if (s0 >= len) return;
    const int steps = min(SEG, len - s0);
    const int qr0 = (d > 0 ? d : 0) + s0;
    const int pr0 = qr0 - d;

    const int a = t >> 2;                          // tile row = qc, 0..63
    const int gcol = t & 3;
    const int b0 = gcol * 16;
    const int kmax = (gcol == 3) ? 14 : 16;        // pc <= 61
    const bool full = (gcol < 3);                  // needs cols b0+16,b0+17
    const bool act = (a < OH);                     // qc <= 61 scores; 62,63 idle

    float G0[16], G1[16], G2[16];
    if (act) {
        gtile(D, qr0 + 0, pr0 + 0, a, b0, full, G0);
        gtile(D, qr0 + 1, pr0 + 1, a, b0, full, G1);
    }

#define SCORE_STEP(K, GA, GB, GC)                                                 \
    if ((K) < steps) {                                                            \
        if (act) gtile(D, qr0 + (K) + 2, pr0 + (K) + 2, a, b0, full, GC);         \
        float best = -1e30f; int bpc = 0;                                         \
        _Pragma("unroll")                                                         \
        for (int kk = 0; kk < 16; ++kk) {                                         \
            float s = GA[kk] + GB[kk] + GC[kk];                                   \
            if (kk < kmax && s > best) { best = s; bpc = b0 + kk; }               \
        }                                                                         \
        float os_; int opc_;                                                      \
        os_ = __shfl_xor(best, 1, 64); opc_ = __shfl_xor(bpc, 1, 64);             \
        if (os_ > best || (os_ == best && opc_ < bpc)) { best = os_; bpc = opc_; }\
        os_ = __shfl_xor(best, 2, 64); opc_ = __shfl_xor(bpc, 2, 64);             \
        if (os_ > best || (os_ == best && opc_ < bpc)) { best = os_; bpc = opc_; }\
        if (act && gcol == 0) {                                                   \
            unsigned u = __float_as_uint(best);                                   \
            u = (best >= 0.f) ? (u | 0x80000000u) : ~u;                           \
            unsigned long long key = ((unsigned long long)u << 12)                \
                                   | (unsigned)((63 - (pr0 + (K))) << 6)          \
                                   | (unsigned)(63 - bpc);                        \
            atomicMax(&keys[(size_t)z * NPATCH + (qr0 + (K)) * OH + a], key);     \
        }                                                                         \
    }

    SCORE_STEP(0, G0, G1, G2)
    SCORE_STEP(1, G1, G2, G0)
    SCORE_STEP(2, G2, G0, G1)
    SCORE_STEP(3, G0, G1, G2)
    SCORE_STEP(4, G1, G2, G0)
    SCORE_STEP(5, G2, G0, G1)
    SCORE_STEP(6, G0, G1, G2)
    SCORE_STEP(7, G1, G2, G0)
#undef SCORE_STEP
}

// -------- K4 (k_loss): decode keys -> match; loss via norm expansion --------
__global__ void k_loss(const unsigned short* __restrict__ Dbase,
                       const unsigned long long* __restrict__ keys,
                       const float* __restrict__ ssPb, const float* __restrict__ invPb,
                       const float* __restrict__ ssTb, const float* __restrict__ invTb,
                       float* __restrict__ out) {
    const int z = blockIdx.y;
    const unsigned short* D = Dbase + (size_t)z * NPIX * NPIX;
    const float* ssP  = ssPb  + z * NPIX;
    const float* invP = invPb + z * NPIX;
    const float* ssT  = ssTb  + z * NPIX;
    const float* invT = invTb + z * NPIX;
    int q = blockIdx.x * 256 + threadIdx.x;
    float acc = 0.f;
    if (q < NPATCH) {
        int qr = q / OH, qc = q - qr * OH;
        int qpix = qr * WW + qc;
        unsigned long long key = keys[(size_t)z * NPATCH + q];
        int mpr = 63 - (int)((key >> 6) & 63);
        int mpc = 63 - (int)(key & 63);
        int mpix = mpr * WW + mpc;
#pragma unroll
        for (int i = 0; i < 3; ++i)
#pragma unroll
            for (int j = 0; j < 3; ++j) {
                int off = i * WW + j;
                int y = qpix + off, x = mpix + off;
                float Dv = bf16_to_f32(D[(size_t)y * NPIX + x]);
                float nP = ssP[y] * invP[y];       // = ||p_y||
                float nT = ssT[x] * invT[x];
                acc += ssP[y] + ssT[x] - 2.f * Dv * nP * nT;
            }
    }
#pragma unroll
    for (int s = 32; s > 0; s >>= 1) acc += __shfl_down(acc, s, 64);
    if ((threadIdx.x & 63) == 0)
        atomicAdd(out, acc * (1.f / 35426304.f));  // / (4*3844*2304)
}

// ---------------------------------- launch ----------------------------------
extern "C" void kernel_launch(void* const* d_in, const int* in_sizes, int n_in,
                              void* d_out, int out_size, void* d_ws, size_t ws_size,
                              hipStream_t stream) {
    const float* pred = (const float*)d_in[0];
    const float* tgt  = (const float*)d_in[1];
    char* ws = (char*)d_ws;
    // ws layout (bytes), ws_size = 256 MiB:
    // D(bf16, 4 batches) 128MB | Xn 8MB | Tn 8MB | norms 4x64KB | keys 123KB
    unsigned short*     Dws  = (unsigned short*)(ws);
    __hip_bfloat16*     Xn   = (__hip_bfloat16*)(ws + 134217728);
    __hip_bfloat16*     Tn   = (__hip_bfloat16*)(ws + 142606336);
    float*              ssP  = (float*)(ws + 150994944);
    float*              invP = (float*)(ws + 151060480);
    float*              ssT  = (float*)(ws + 151126016);
    float*              invT = (float*)(ws + 151191552);
    unsigned long long* keys = (unsigned long long*)(ws + 151257088);

    k_prep<<<dim3(64, 8), 256, 0, stream>>>(pred, tgt, Xn, Tn, ssP, invP, ssT, invT,
                                            keys, (float*)d_out);
    k_gemm<<<dim3(32, 32, 1), 256, 0, stream>>>(Xn, Tn, Dws, 0);
    k_gemm<<<dim3(32, 32, 1), 256, 0, stream>>>(Xn, Tn, Dws, 1);
    k_gemm<<<dim3(32, 32, 1), 256, 0, stream>>>(Xn, Tn, Dws, 2);
    k_gemm<<<dim3(32, 32, 1), 256, 0, stream>>>(Xn, Tn, Dws, 3);
    k_score<<<dim3(123, 2, 4), 256, 0, stream>>>(Dws, keys, 0);
    k_score<<<dim3(123, 2, 4), 256, 0, stream>>>(Dws, keys, 1);
    k_score<<<dim3(123, 2, 4), 256, 0, stream>>>(Dws, keys, 2);
    k_score<<<dim3(123, 2, 4), 256, 0, stream>>>(Dws, keys, 3);
    k_loss<<<dim3(16, 4), 256, 0, stream>>>(Dws, keys, ssP, invP, ssT, invT,
                                            (float*)d_out);
}

// Round 8
// 180.077 us; speedup vs baseline: 1.3004x; 1.3004x over previous
//
#include <hip/hip_runtime.h>
#include <hip/hip_bf16.h>

#define NB 4
#define CH 256
#define HH 64
#define WW 64
#define NPIX 4096      // HH*WW
#define OH 62
#define NPATCH 3844    // 62*62
#define KDIM 256       // == CH
#define EPSN 1e-12f
#define SEG 16         // diagonal segment length (row-pairs per block) — R8: 8->16
#define PST 68         // k_prep stage row stride (shorts): 8B-aligned rows

typedef __attribute__((ext_vector_type(8))) short short8;
typedef __attribute__((ext_vector_type(4))) float f32x4;

__device__ __forceinline__ float bf16_to_f32(unsigned short u) {
    return __uint_as_float((unsigned)u << 16);
}
__device__ __forceinline__ unsigned short f32_to_bf16(float f) {
    __hip_bfloat16 h = __float2bfloat16(f);
    return *(unsigned short*)&h;
}

// ---- K1 (fused prep): read inputs ONCE; per-pixel ss + inv-norm; normalized bf16
// ---- transpose (C,pix)->(pix,C). Also zero-inits d_out + keys.
__global__ __launch_bounds__(256) void k_prep(const float* __restrict__ pred,
                                              const float* __restrict__ tgt,
                                              __hip_bfloat16* __restrict__ Xn,
                                              __hip_bfloat16* __restrict__ Tn,
                                              float* __restrict__ ssP, float* __restrict__ invP,
                                              float* __restrict__ ssT, float* __restrict__ invT,
                                              unsigned long long* __restrict__ keys,
                                              float* __restrict__ out) {
    const int bz = blockIdx.y;            // 0..7
    const int b = bz >> 1, which = bz & 1;
    const float* src = (which ? tgt : pred) + (size_t)b * CH * NPIX;
    unsigned short* dst = (unsigned short*)((which ? Tn : Xn) + (size_t)b * NPIX * CH);
    float* ss_g  = (which ? ssT  : ssP)  + b * NPIX;
    float* inv_g = (which ? invT : invP) + b * NPIX;
    const int pix0 = blockIdx.x * 64;
    const int t = threadIdx.x, lane = t & 63, wv = t >> 6;

    int gid = (bz * 64 + blockIdx.x) * 256 + t;
    if (gid < NB * NPATCH) keys[gid] = 0ull;
    if (gid == 0) out[0] = 0.f;

    __shared__ unsigned short stage[CH][PST];  // 34816 B
    __shared__ float partial[16][68];          // 4352 B (+pad: 2-way reads)
    __shared__ float inv_s[64];

    // load: thread (cb = t>>4, ch = t&15) covers c = cb*16+r (r<16), pixels ch*4..+3
    const int cb = t >> 4, chk = t & 15;
    float ss0 = 0.f, ss1 = 0.f, ss2 = 0.f, ss3 = 0.f;
#pragma unroll
    for (int r = 0; r < 16; ++r) {
        int c = cb * 16 + r;
        float4 v = *(const float4*)&src[(size_t)c * NPIX + pix0 + chk * 4];
        ss0 += v.x * v.x; ss1 += v.y * v.y; ss2 += v.z * v.z; ss3 += v.w * v.w;
        ushort4 sv;
        sv.x = f32_to_bf16(v.x); sv.y = f32_to_bf16(v.y);
        sv.z = f32_to_bf16(v.z); sv.w = f32_to_bf16(v.w);
        *(ushort4*)&stage[c][chk * 4] = sv;
    }
    float4 pv; pv.x = ss0; pv.y = ss1; pv.z = ss2; pv.w = ss3;
    *(float4*)&partial[cb][chk * 4] = pv;
    __syncthreads();
    if (t < 64) {
        float ss = 0.f;
#pragma unroll
        for (int r = 0; r < 16; ++r) ss += partial[r][t];
        float inv = 1.f / fmaxf(sqrtf(ss), EPSN);
        ss_g[pix0 + t] = ss;
        inv_g[pix0 + t] = inv;
        inv_s[t] = inv;
    }
    __syncthreads();
    // write: pixel p (16/wave), lane = c within 64-chunk; 2-way-free LDS reads
    for (int p = wv; p < 64; p += 4) {
        float iv = inv_s[p];
#pragma unroll
        for (int cc = 0; cc < 4; ++cc) {
            int c = cc * 64 + lane;
            float v = bf16_to_f32(stage[c][p]) * iv;
            dst[(size_t)(pix0 + p) * CH + c] = f32_to_bf16(v);
        }
    }
}

// ------- K2: D = Xn * Tn^T (4096x4096, K=256, bf16 MFMA, bf16 OUTPUT).
// LOCKED: exact R1 kernel (57.3 us, three independent confirmations; R2/R4
// reshapes failed). R8: back to ONE dispatch (z in grid) — R7 measured ~54 us
// total cost for split dispatches (drain boundaries + lost TLP).
__device__ __forceinline__ void gload_lds16(const void* g, void* l) {
    __builtin_amdgcn_global_load_lds(
        (const __attribute__((address_space(1))) void*)g,
        (__attribute__((address_space(3))) void*)l, 16, 0, 0);
}

__global__ __launch_bounds__(256, 2) void k_gemm(const __hip_bfloat16* __restrict__ A,
                                                 const __hip_bfloat16* __restrict__ Bm,
                                                 unsigned short* __restrict__ Dout) {
    // one 64 KB arena: As buf0 [0,8192), As buf1 [8192,16384),
    //                  Bs buf0 [16384,24576), Bs buf1 [24576,32768) (shorts)
    __shared__ __align__(16) short smem[32768];
#define ASOFF(buf) ((buf) * 8192)
#define BSOFF(buf) (16384 + (buf) * 8192)

    const int t = threadIdx.x;
    const int lane = t & 63, wv = t >> 6;          // 4 waves
    const int wm = wv >> 1, wn = wv & 1;           // 2x2 wave grid, 64x64 each

    // XCD-bijective swizzle over 4096 blocks (nwg%8==0)
    const int bid = ((blockIdx.z << 5) + blockIdx.y) * 32 + blockIdx.x;  // 0..4095
    const int swz = ((bid & 7) << 9) + (bid >> 3);
    const int z = swz >> 10, by = (swz >> 5) & 31, bx = swz & 31;

    const int row0 = by * 128, col0 = bx * 128;
    const short* Ag = (const short*)A + (size_t)z * NPIX * CH;
    const short* Bg = (const short*)Bm + (size_t)z * NPIX * CH;
    unsigned short* D = Dout + (size_t)z * NPIX * NPIX;

    const int srow = t >> 3;                        // 0..31 (staging row within round)
    const int kce  = ((t & 7) ^ (srow & 7)) * 8;    // pre-swizzled k offset within BK=64

    f32x4 acc[4][4] = {};

    // stage one BK=64 K-slab of A(128x64) + B(128x64): 4 rounds each, 8 loads/thread
#define STAGE_K(buf, k0)                                                                   \
    do {                                                                                   \
        _Pragma("unroll")                                                                  \
        for (int rr_ = 0; rr_ < 4; ++rr_)                                                  \
            gload_lds16(Ag + (size_t)(row0 + rr_ * 32 + srow) * KDIM + (k0) + kce,         \
                        &smem[ASOFF(buf) + rr_ * 2048 + wv * 512]);                        \
        _Pragma("unroll")                                                                  \
        for (int rr_ = 0; rr_ < 4; ++rr_)                                                  \
            gload_lds16(Bg + (size_t)(col0 + rr_ * 32 + srow) * KDIM + (k0) + kce,         \
                        &smem[BSOFF(buf) + rr_ * 2048 + wv * 512]);                        \
    } while (0)

    const int rsel = lane & 15, kq = lane >> 4;
    const int rx = rsel & 7;

#define CONSUME(buf)                                                                       \
    do {                                                                                   \
        _Pragma("unroll")                                                                  \
        for (int s = 0; s < 2; ++s) {                                                      \
            const int pk = (((s << 2) + kq) ^ rx) * 8;                                     \
            short8 a_[4], b_[4];                                                           \
            _Pragma("unroll")                                                              \
            for (int mi = 0; mi < 4; ++mi)                                                 \
                a_[mi] = *(const short8*)&smem[ASOFF(buf) + (wm * 64 + mi * 16 + rsel) * 64 + pk]; \
            _Pragma("unroll")                                                              \
            for (int ni = 0; ni < 4; ++ni)                                                 \
                b_[ni] = *(const short8*)&smem[BSOFF(buf) + (wn * 64 + ni * 16 + rsel) * 64 + pk]; \
            _Pragma("unroll")                                                              \
            for (int mi = 0; mi < 4; ++mi)                                                 \
                _Pragma("unroll")                                                          \
                for (int ni = 0; ni < 4; ++ni)                                             \
                    acc[mi][ni] = __builtin_amdgcn_mfma_f32_16x16x32_bf16(a_[mi], b_[ni],  \
                                                                          acc[mi][ni], 0, 0, 0); \
        }                                                                                  \
    } while (0)

#define KITER(it, VMC)                                              \
    do {                                                            \
        asm volatile("s_waitcnt vmcnt(" #VMC ")" ::: "memory");     \
        __builtin_amdgcn_sched_barrier(0);                          \
        __builtin_amdgcn_s_barrier();                               \
        __builtin_amdgcn_sched_barrier(0);                          \
        CONSUME((it) & 1);                                          \
        asm volatile("s_waitcnt lgkmcnt(0)" ::: "memory");          \
        __builtin_amdgcn_sched_barrier(0);                          \
        __builtin_amdgcn_s_barrier();                               \
        __builtin_amdgcn_sched_barrier(0);                          \
        if ((it) < 2) STAGE_K((it) & 1, ((it) + 2) * 64);           \
    } while (0)

    STAGE_K(0, 0);
    STAGE_K(1, 64);        // 16 loads in flight
    KITER(0, 8);
    KITER(1, 8);
    KITER(2, 8);
    KITER(3, 0);
#undef KITER
#undef CONSUME
#undef STAGE_K

    // ---- epilogue: stage C tile (128x128 bf16, 32 KB) in LDS, store dwordx4 ----
    const int rbase = (lane >> 4) * 4, cbase = lane & 15;
    unsigned short* Cs = (unsigned short*)smem;
#pragma unroll
    for (int mi = 0; mi < 4; ++mi)
#pragma unroll
        for (int ni = 0; ni < 4; ++ni) {
            int c = wn * 64 + ni * 16 + cbase;
#pragma unroll
            for (int r = 0; r < 4; ++r) {
                int row = wm * 64 + mi * 16 + rbase + r;
                int pc = (((c >> 3) ^ (row & 15)) * 8) + (c & 7);
                Cs[row * 128 + pc] = f32_to_bf16(acc[mi][ni][r]);
            }
        }
    __syncthreads();
#pragma unroll
    for (int rd = 0; rd < 8; ++rd) {
        int rr = rd * 16 + (t >> 4);
        int pc = ((t & 15) ^ (rr & 15)) * 8;
        uint4 v = *(const uint4*)&Cs[rr * 128 + pc];
        *(uint4*)&D[(size_t)(row0 + rr) * NPIX + col0 + (t & 15) * 8] = v;
    }
#undef ASOFF
#undef BSOFF
}

// ---- K3 (k_score): barrier-free, LDS-free streaming formulation (R6).
// R8: ONE dispatch again; SEG 8->16 — prologue tile-loads halve (2 per segment,
// segments per diagonal halve: ~11% fewer total tile loads), longer
// register-resident streams. Same registers (rotation is static), same
// arithmetic and sum order as R6.
__device__ __forceinline__ void load_row18(const unsigned short* __restrict__ rp,
                                           bool full, float* o) {
    uint4 u0 = *(const uint4*)rp;          // cols 0..7
    uint4 u1 = *(const uint4*)(rp + 8);    // cols 8..15
    unsigned e = full ? *(const unsigned*)(rp + 16) : 0u;  // cols 16,17
    const unsigned* w0 = (const unsigned*)&u0;
    const unsigned* w1 = (const unsigned*)&u1;
#pragma unroll
    for (int w = 0; w < 4; ++w) {
        o[2 * w]         = bf16_to_f32((unsigned short)w0[w]);
        o[2 * w + 1]     = bf16_to_f32((unsigned short)(w0[w] >> 16));
        o[8 + 2 * w]     = bf16_to_f32((unsigned short)w1[w]);
        o[8 + 2 * w + 1] = bf16_to_f32((unsigned short)(w1[w] >> 16));
    }
    o[16] = bf16_to_f32((unsigned short)e);
    o[17] = bf16_to_f32((unsigned short)(e >> 16));
}

__device__ __forceinline__ void gtile(const unsigned short* __restrict__ D,
                                      int tr, int tc, int a, int b0, bool full,
                                      float* G) {
    const unsigned short* base = D + (size_t)(tr * 64 + a) * NPIX + tc * 64 + b0;
    float r0[18], r1[18], r2[18];
    load_row18(base, full, r0);
    load_row18(base + NPIX, full, r1);
    load_row18(base + 2 * NPIX, full, r2);
#pragma unroll
    for (int kk = 0; kk < 16; ++kk)
        G[kk] = r0[kk] + r1[kk + 1] + r2[kk + 2];
}

__global__ __launch_bounds__(256) void k_score(const unsigned short* __restrict__ Dbase,
                                               unsigned long long* __restrict__ keys) {
    const int z = blockIdx.z;
    const unsigned short* D = Dbase + (size_t)z * NPIX * NPIX;
    const int t = threadIdx.x;

    const int d = (int)blockIdx.x - 61;            // diagonal qr-pr in [-61, 61]
    const int adg = d < 0 ? -d : d;
    const int len = 62 - adg;
    const int s0 = blockIdx.y * SEG;
    if (s0 >= len) return;
    const int steps = min(SEG, len - s0);
    const int qr0 = (d > 0 ? d : 0) + s0;
    const int pr0 = qr0 - d;

    const int a = t >> 2;                          // tile row = qc, 0..63
    const int gcol = t & 3;
    const int b0 = gcol * 16;
    const int kmax = (gcol == 3) ? 14 : 16;        // pc <= 61
    const bool full = (gcol < 3);                  // needs cols b0+16,b0+17
    const bool act = (a < OH);                     // qc <= 61 scores; 62,63 idle

    float G0[16], G1[16], G2[16];
    if (act) {
        gtile(D, qr0 + 0, pr0 + 0, a, b0, full, G0);
        gtile(D, qr0 + 1, pr0 + 1, a, b0, full, G1);
    }

#define SCORE_STEP(K, GA, GB, GC)                                                 \
    if ((K) < steps) {                                                            \
        if (act) gtile(D, qr0 + (K) + 2, pr0 + (K) + 2, a, b0, full, GC);         \
        float best = -1e30f; int bpc = 0;                                         \
        _Pragma("unroll")                                                         \
        for (int kk = 0; kk < 16; ++kk) {                                         \
            float s = GA[kk] + GB[kk] + GC[kk];                                   \
            if (kk < kmax && s > best) { best = s; bpc = b0 + kk; }               \
        }                                                                         \
        float os_; int opc_;                                                      \
        os_ = __shfl_xor(best, 1, 64); opc_ = __shfl_xor(bpc, 1, 64);             \
        if (os_ > best || (os_ == best && opc_ < bpc)) { best = os_; bpc = opc_; }\
        os_ = __shfl_xor(best, 2, 64); opc_ = __shfl_xor(bpc, 2, 64);             \
        if (os_ > best || (os_ == best && opc_ < bpc)) { best = os_; bpc = opc_; }\
        if (act && gcol == 0) {                                                   \
            unsigned u = __float_as_uint(best);                                   \
            u = (best >= 0.f) ? (u | 0x80000000u) : ~u;                           \
            unsigned long long key = ((unsigned long long)u << 12)                \
                                   | (unsigned)((63 - (pr0 + (K))) << 6)          \
                                   | (unsigned)(63 - bpc);                        \
            atomicMax(&keys[(size_t)z * NPATCH + (qr0 + (K)) * OH + a], key);     \
        }                                                                         \
    }

    SCORE_STEP(0,  G0, G1, G2)
    SCORE_STEP(1,  G1, G2, G0)
    SCORE_STEP(2,  G2, G0, G1)
    SCORE_STEP(3,  G0, G1, G2)
    SCORE_STEP(4,  G1, G2, G0)
    SCORE_STEP(5,  G2, G0, G1)
    SCORE_STEP(6,  G0, G1, G2)
    SCORE_STEP(7,  G1, G2, G0)
    SCORE_STEP(8,  G2, G0, G1)
    SCORE_STEP(9,  G0, G1, G2)
    SCORE_STEP(10, G1, G2, G0)
    SCORE_STEP(11, G2, G0, G1)
    SCORE_STEP(12, G0, G1, G2)
    SCORE_STEP(13, G1, G2, G0)
    SCORE_STEP(14, G2, G0, G1)
    SCORE_STEP(15, G0, G1, G2)
#undef SCORE_STEP
}

// -------- K4 (k_loss): decode keys -> match; loss via norm expansion --------
__global__ void k_loss(const unsigned short* __restrict__ Dbase,
                       const unsigned long long* __restrict__ keys,
                       const float* __restrict__ ssPb, const float* __restrict__ invPb,
                       const float* __restrict__ ssTb, const float* __restrict__ invTb,
                       float* __restrict__ out) {
    const int z = blockIdx.y;
    const unsigned short* D = Dbase + (size_t)z * NPIX * NPIX;
    const float* ssP  = ssPb  + z * NPIX;
    const float* invP = invPb + z * NPIX;
    const float* ssT  = ssTb  + z * NPIX;
    const float* invT = invTb + z * NPIX;
    int q = blockIdx.x * 256 + threadIdx.x;
    float acc = 0.f;
    if (q < NPATCH) {
        int qr = q / OH, qc = q - qr * OH;
        int qpix = qr * WW + qc;
        unsigned long long key = keys[(size_t)z * NPATCH + q];
        int mpr = 63 - (int)((key >> 6) & 63);
        int mpc = 63 - (int)(key & 63);
        int mpix = mpr * WW + mpc;
#pragma unroll
        for (int i = 0; i < 3; ++i)
#pragma unroll
            for (int j = 0; j < 3; ++j) {
                int off = i * WW + j;
                int y = qpix + off, x = mpix + off;
                float Dv = bf16_to_f32(D[(size_t)y * NPIX + x]);
                float nP = ssP[y] * invP[y];       // = ||p_y||
                float nT = ssT[x] * invT[x];
                acc += ssP[y] + ssT[x] - 2.f * Dv * nP * nT;
            }
    }
#pragma unroll
    for (int s = 32; s > 0; s >>= 1) acc += __shfl_down(acc, s, 64);
    if ((threadIdx.x & 63) == 0)
        atomicAdd(out, acc * (1.f / 35426304.f));  // / (4*3844*2304)
}

// ---------------------------------- launch ----------------------------------
extern "C" void kernel_launch(void* const* d_in, const int* in_sizes, int n_in,
                              void* d_out, int out_size, void* d_ws, size_t ws_size,
                              hipStream_t stream) {
    const float* pred = (const float*)d_in[0];
    const float* tgt  = (const float*)d_in[1];
    char* ws = (char*)d_ws;
    // ws layout (bytes), ws_size = 256 MiB:
    // D(bf16, 4 batches) 128MB | Xn 8MB | Tn 8MB | norms 4x64KB | keys 123KB
    unsigned short*     Dws  = (unsigned short*)(ws);
    __hip_bfloat16*     Xn   = (__hip_bfloat16*)(ws + 134217728);
    __hip_bfloat16*     Tn   = (__hip_bfloat16*)(ws + 142606336);
    float*              ssP  = (float*)(ws + 150994944);
    float*              invP = (float*)(ws + 151060480);
    float*              ssT  = (float*)(ws + 151126016);
    float*              invT = (float*)(ws + 151191552);
    unsigned long long* keys = (unsigned long long*)(ws + 151257088);

    k_prep<<<dim3(64, 8), 256, 0, stream>>>(pred, tgt, Xn, Tn, ssP, invP, ssT, invT,
                                            keys, (float*)d_out);
    k_gemm<<<dim3(32, 32, 4), 256, 0, stream>>>(Xn, Tn, Dws);
    k_score<<<dim3(123, 4, 4), 256, 0, stream>>>(Dws, keys);
    k_loss<<<dim3(16, 4), 256, 0, stream>>>(Dws, keys, ssP, invP, ssT, invT,
                                            (float*)d_out);
}